// Round 11
// baseline (102.251 us; speedup 1.0000x reference)
//
#include <hip/hip_runtime.h>
#include <hip/hip_bf16.h>
#include <hip/hip_cooperative_groups.h>
#include <stdint.h>

// ContrastiveLoss (R11): ONE cooperative kernel = convert + gridsync +
// 256^2 deep-pipelined GEMM + last-block finalize.
//   d2[b,j,k] = a2[b,j] + b2[b,k] - 2*(A_b . B_b^T)[j,k]
//   loss = sum_{j!=k} [ max(d2,0) + max(1-sqrt(max(d2,0)),0)^2 ] / (B*N*(N-1))
//
// R10 evidence: all 4 gemm structures cluster at 25-40us bench despite ~3us
// of modeled work; fit across R1-R10 says ~10us/launch overhead dominates.
// R11 collapses 3 launches -> 1 cooperative launch (guide-sanctioned):
//   - 256 blocks x 512 thr, 128.5KB LDS -> 1 block/CU, all co-resident.
//   - blk = batch + 16*tile -> blk%8 = batch%8: all 16 tile-blocks of a
//     batch share an XCD; phase 1 converts the SAME batch's data the XCD
//     consumes in phase 2 (L2-hot).
//   - phase 3: atomic done-counter; last block reduces 256 partials
//     (fixed-order -> deterministic); counter reset by blk0 in phase 1
//     (ws is poisoned once, never re-poisoned).

namespace cg = cooperative_groups;

#define BATCH 16
#define NDIM  1024
#define DDIM  512

typedef __attribute__((ext_vector_type(8))) short short8;
typedef __attribute__((ext_vector_type(4))) float floatx4;

__device__ __forceinline__ ushort f2bf(float f) {
    uint32_t x = __float_as_uint(f);
    uint32_t r = (x + 0x7FFFu + ((x >> 16) & 1u)) >> 16;  // RNE
    return (ushort)r;
}

__global__ __launch_bounds__(512, 2) void pairloss_all(
    const float* __restrict__ a, const float* __restrict__ b,
    ushort* __restrict__ abf, ushort* __restrict__ bbf,
    float* __restrict__ a2, float* __restrict__ b2,
    float2* __restrict__ partials, unsigned* __restrict__ counter,
    float* __restrict__ out) {
    __shared__ ushort sAB[2][2][256][64];   // [buf][op][row][col] = 128 KB
    __shared__ float red[16];
    __shared__ double dred[8];
    __shared__ unsigned lastflag;

    const int tid  = threadIdx.x;
    const int lane = tid & 63;
    const int wid  = tid >> 6;              // 0..7
    const int blk   = blockIdx.x;           // batch + 16*tile
    const int batch = blk & 15;
    const int tile  = blk >> 4;             // 0..15
    const int rowt  = tile >> 2;            // 0..3
    const int colt  = tile & 3;             // 0..3

    if (blk == 0 && tid == 0) *counter = 0u;   // reset done-counter (pre-sync)

    // ================= Phase 1: convert 64 rows of A and B ================
    // Block converts rows [tile*64, tile*64+64) of its batch for BOTH
    // arrays (256KB f32 -> 128KB bf16) + exact f32 row sum-of-squares.
    {
        const size_t row0 = (size_t)batch * NDIM + tile * 64;
        #pragma unroll 1
        for (int s = 0; s < 2; ++s) {
            const float* src = s ? b : a;
            ushort* dst      = s ? bbf : abf;
            float* s2        = s ? b2 : a2;
            #pragma unroll 1
            for (int rr = 0; rr < 8; ++rr) {
                const size_t row = row0 + wid * 8 + rr;
                const float4* srow = reinterpret_cast<const float4*>(src + row * DDIM);
                float4 v0 = srow[lane];
                float4 v1 = srow[64 + lane];
                float ss = v0.x*v0.x + v0.y*v0.y + v0.z*v0.z + v0.w*v0.w
                         + v1.x*v1.x + v1.y*v1.y + v1.z*v1.z + v1.w*v1.w;
                ushort4 u0; u0.x = f2bf(v0.x); u0.y = f2bf(v0.y);
                            u0.z = f2bf(v0.z); u0.w = f2bf(v0.w);
                ushort4 u1; u1.x = f2bf(v1.x); u1.y = f2bf(v1.y);
                            u1.z = f2bf(v1.z); u1.w = f2bf(v1.w);
                ushort* drow = dst + row * DDIM;
                *reinterpret_cast<ushort4*>(drow + lane * 4)       = u0;
                *reinterpret_cast<ushort4*>(drow + 256 + lane * 4) = u1;
                #pragma unroll
                for (int off = 32; off > 0; off >>= 1) ss += __shfl_xor(ss, off, 64);
                if (lane == 0) s2[row] = ss;
            }
        }
    }

    cg::this_grid().sync();

    // ================= Phase 2: 256x256 tile GEMM (R10 body) =============
    const size_t arow0 = (size_t)batch * NDIM + rowt * 256;
    const size_t brow0 = (size_t)batch * NDIM + colt * 256;

    auto stage = [&](int p, int kt) {
        #pragma unroll
        for (int i = 0; i < 8; ++i) {
            const int q    = i * 512 + tid;
            const int op   = q >> 11;                // 0..3 -> A, 4..7 -> B
            const int row  = (q & 2047) >> 3;
            const int slot = q & 7;
            const int gcol = kt * 64 + ((slot ^ (row & 7)) << 3);
            const ushort* src = (op ? bbf + (brow0 + row) * DDIM + gcol
                                    : abf + (arow0 + row) * DDIM + gcol);
            __builtin_amdgcn_global_load_lds(
                (const __attribute__((address_space(1))) void*)src,
                (__attribute__((address_space(3))) void*)&sAB[p][op][row][slot * 8],
                16, 0, 0);
        }
    };

    floatx4 acc[8][4];
    #pragma unroll
    for (int m = 0; m < 8; ++m)
        #pragma unroll
        for (int cf = 0; cf < 4; ++cf) acc[m][cf] = 0.0f;

    const int wr = (wid >> 2) * 128;        // wave row base in tile
    const int wc = (wid & 3) * 64;          // wave col base in tile

    stage(0, 0);
    stage(1, 1);
    asm volatile("s_waitcnt vmcnt(8)" ::: "memory");   // T0 landed
    __builtin_amdgcn_s_barrier();
    __builtin_amdgcn_sched_barrier(0);

    #pragma unroll 1
    for (int kt = 0; kt < 8; ++kt) {
        const int p = kt & 1;
        #pragma unroll
        for (int kk = 0; kk < 2; ++kk) {
            short8 af[8], bfr[4];
            #pragma unroll
            for (int m = 0; m < 8; ++m) {
                const int row  = wr + m * 16 + (lane & 15);
                const int slot = (kk * 4 + (lane >> 4)) ^ (row & 7);
                af[m] = *reinterpret_cast<const short8*>(&sAB[p][0][row][slot * 8]);
            }
            #pragma unroll
            for (int cf = 0; cf < 4; ++cf) {
                const int row  = wc + cf * 16 + (lane & 15);
                const int slot = (kk * 4 + (lane >> 4)) ^ (row & 7);
                bfr[cf] = *reinterpret_cast<const short8*>(&sAB[p][1][row][slot * 8]);
            }
            __builtin_amdgcn_s_setprio(1);
            #pragma unroll
            for (int m = 0; m < 8; ++m)
                #pragma unroll
                for (int cf = 0; cf < 4; ++cf)
                    acc[m][cf] = __builtin_amdgcn_mfma_f32_16x16x32_bf16(
                        af[m], bfr[cf], acc[m][cf], 0, 0, 0);
            __builtin_amdgcn_s_setprio(0);
        }
        __builtin_amdgcn_s_barrier();           // all waves done reading buf p
        __builtin_amdgcn_sched_barrier(0);
        if (kt + 2 < 8) stage(p, kt + 2);       // refill freed buffer (async)
        if (kt + 1 < 8) {
            if (kt + 2 < 8) asm volatile("s_waitcnt vmcnt(8)" ::: "memory");
            else            asm volatile("s_waitcnt vmcnt(0)" ::: "memory");
            __builtin_amdgcn_s_barrier();
            __builtin_amdgcn_sched_barrier(0);
        }
    }

    // ---- epilogue: d2 = a2[row] + b2[col] - 2*ab, off-diag masked sums ----
    float pos = 0.0f, neg = 0.0f;
    {
        const float* a2p = a2 + arow0;
        const float* b2p = b2 + brow0;
        const int rbase = rowt * 256;
        const int cbase = colt * 256;
        #pragma unroll
        for (int m = 0; m < 8; ++m) {
            const int r0 = wr + m * 16 + (lane >> 4) * 4;
            #pragma unroll
            for (int cf = 0; cf < 4; ++cf) {
                const int cc = wc + cf * 16 + (lane & 15);
                const float bb = b2p[cc];
                #pragma unroll
                for (int j = 0; j < 4; ++j) {
                    const int rr = r0 + j;
                    float d2 = a2p[rr] + bb - 2.0f * acc[m][cf][j];
                    d2 = fmaxf(d2, 0.0f);
                    if (rbase + rr != cbase + cc) {
                        pos += d2;
                        if (d2 < 1.0f) {     // hinge active (rare)
                            float h = 1.0f - sqrtf(d2);
                            neg += h * h;
                        }
                    }
                }
            }
        }
    }

    #pragma unroll
    for (int off = 32; off > 0; off >>= 1) {
        pos += __shfl_xor(pos, off, 64);
        neg += __shfl_xor(neg, off, 64);
    }
    if (lane == 0) { red[wid * 2] = pos; red[wid * 2 + 1] = neg; }
    __syncthreads();

    // ================= Phase 3: last-block finalize ======================
    if (tid == 0) {
        float p = 0.0f, q = 0.0f;
        #pragma unroll
        for (int w = 0; w < 8; ++w) { p += red[w * 2]; q += red[w * 2 + 1]; }
        partials[blk] = make_float2(p, q);
        __threadfence();
        lastflag = atomicAdd(counter, 1u);
    }
    __syncthreads();
    if (lastflag == 255u) {                 // this block is last: reduce all
        __threadfence();
        double p = 0.0, q = 0.0;
        if (tid < 256) {
            float2 v = partials[tid];
            p = (double)v.x; q = (double)v.y;
        }
        #pragma unroll
        for (int off = 32; off > 0; off >>= 1) {
            p += __shfl_xor(p, off, 64);
            q += __shfl_xor(q, off, 64);
        }
        if (lane == 0) { dred[wid] = p + q; }
        __syncthreads();
        if (tid == 0) {
            double t = 0.0;
            #pragma unroll
            for (int w = 0; w < 8; ++w) t += dred[w];
            const double n_neg = (double)BATCH * NDIM * (NDIM - 1);
            out[0] = (float)(t / n_neg);
        }
    }
}

extern "C" void kernel_launch(void* const* d_in, const int* in_sizes, int n_in,
                              void* d_out, int out_size, void* d_ws, size_t ws_size,
                              hipStream_t stream) {
    const float* a = (const float*)d_in[0];
    const float* b = (const float*)d_in[1];
    float* out = (float*)d_out;

    const size_t NELEM = (size_t)BATCH * NDIM * DDIM;   // 8,388,608
    ushort* abf = (ushort*)d_ws;
    ushort* bbf = abf + NELEM;
    float*  a2  = (float*)(bbf + NELEM);
    float*  b2  = a2 + BATCH * NDIM;
    float2* partials = (float2*)(b2 + BATCH * NDIM);
    unsigned* counter = (unsigned*)(partials + 256);

    void* args[] = {(void*)&a, (void*)&b, (void*)&abf, (void*)&bbf,
                    (void*)&a2, (void*)&b2, (void*)&partials,
                    (void*)&counter, (void*)&out};
    hipLaunchCooperativeKernel((const void*)pairloss_all,
                               dim3(256), dim3(512), args, 0, stream);
}